// Round 6
// baseline (262.493 us; speedup 1.0000x reference)
//
#include <hip/hip_runtime.h>
#include <stdint.h>

#define NN 50000
#define NE 800000
#define D  128
#define NEG_INIT -1e9f

// ---------------- ws layout (int offsets) ----------------
#define FLAGS_OFF 0                       // [0]=f32 flag, [1]=i64 flag
#define OFF_OFF   64                      // NN+1 CSR row offsets
#define CUR_OFF   50176                   // NN counters / cursors
#define BKT_OFF   100224                  // NE packed entries: (w_bf16<<16)|src
#define XBF_OFF   900224                  // NN*D bf16 x = 3.2M ints
#define WBF_OFF   4100224                 // w1+w2 bf16 = 32768 ushort = 16384 ints
#define BSUM_OFF  4116608                 // 256 ints scan partials
// total: 4,116,864 ints = 16.5 MB (well under 32.4 MB proven available)

#define NBLK 196                          // ceil((NN+1)/256)
#define HSTRIDE 136                       // LDS row stride in ushorts (272 B, 2-way banks = free)

typedef __attribute__((ext_vector_type(8))) short short8;
typedef __attribute__((ext_vector_type(4))) float float4v;

// ---------------- bf16 helpers ----------------
__device__ __forceinline__ float b2f(uint16_t u) {
    union { uint32_t u; float f; } v; v.u = ((uint32_t)u) << 16; return v.f;
}
__device__ __forceinline__ uint16_t f2b(float f) {
    union { float f; uint32_t u; } v; v.f = f;
    uint32_t r = v.u + 0x7fffu + ((v.u >> 16) & 1u);   // RNE
    return (uint16_t)(r >> 16);
}

// ---------------- kernel 0: runtime dtype probe (PROVEN rounds 2-4; load-bearing) ----------------
__global__ void probe_kernel(const uint16_t* __restrict__ xraw,
                             const int* __restrict__ eraw,
                             int* __restrict__ flags) {
    int t = threadIdx.x;   // 64 threads
    float v0 = b2f(xraw[2 * t]);
    float v1 = b2f(xraw[2 * t + 1]);
    int bad = (!(v0 > -1e4f && v0 < 1e4f)) || (!(v1 > -1e4f && v1 < 1e4f));
    unsigned long long bm = __ballot(bad);
    int nz = (t < 32) ? (eraw[2 * t + 1] != 0) : 0;
    unsigned long long im = __ballot(nz);
    if (t == 0) { flags[0] = bm ? 1 : 0; flags[1] = im ? 0 : 1; }
}

// ---------------- fused prep: x->bf16 | w1,w2->bf16 | zero counters ----------------
// grid = 6250 (x) + 32 (w) + NBLK (zero) = 6478 blocks
__global__ __launch_bounds__(256) void prep_kernel(
    const uint16_t* __restrict__ xraw,
    const uint16_t* __restrict__ w1raw,
    const uint16_t* __restrict__ w2raw,
    int* __restrict__ ws)
{
    int bid = blockIdx.x;
    const int f32 = ws[0];
    if (bid < 6250) {
        int i4 = (bid * 256 + threadIdx.x) * 4;          // covers NN*D = 6.4M exactly
        ushort* dst = (ushort*)(ws + XBF_OFF);
        if (f32) {
            float4 v = *(const float4*)((const float*)xraw + i4);
            ushort4 o; o.x = f2b(v.x); o.y = f2b(v.y); o.z = f2b(v.z); o.w = f2b(v.w);
            *(ushort4*)(dst + i4) = o;
        } else {
            *(ushort4*)(dst + i4) = *(const ushort4*)(xraw + i4);
        }
    } else if (bid < 6282) {
        int i4 = ((bid - 6250) * 256 + threadIdx.x) * 4; // 0..32764
        const uint16_t* src = (i4 < 16384) ? w1raw : w2raw;
        int off = i4 & 16383;
        ushort* dst = (ushort*)(ws + WBF_OFF);
        if (f32) {
            float4 v = *(const float4*)((const float*)src + off);
            ushort4 o; o.x = f2b(v.x); o.y = f2b(v.y); o.z = f2b(v.z); o.w = f2b(v.w);
            *(ushort4*)(dst + i4) = o;
        } else {
            *(ushort4*)(dst + i4) = *(const ushort4*)(src + off);
        }
    } else {
        int i = (bid - 6282) * 256 + threadIdx.x;
        if (i < NN) ws[CUR_OFF + i] = 0;
    }
}

// ---------------- CSR build ----------------
__global__ void hist_kernel(const int* __restrict__ eraw, int* __restrict__ ws) {
    int e = blockIdx.x * 256 + threadIdx.x;              // grid NE/256 = 3125 exact
    int dst = ws[1] ? (int)((const long long*)eraw)[NE + e] : eraw[NE + e];
    if ((unsigned)dst < NN) atomicAdd(ws + CUR_OFF + dst, 1);
}

__global__ __launch_bounds__(256) void scan_bsum(int* __restrict__ ws) {
    __shared__ int s[256];
    int t = threadIdx.x;
    int idx = blockIdx.x * 256 + t;
    s[t] = (idx < NN) ? ws[CUR_OFF + idx] : 0;
    __syncthreads();
    for (int d = 128; d > 0; d >>= 1) {
        if (t < d) s[t] += s[t + d];
        __syncthreads();
    }
    if (t == 0) ws[BSUM_OFF + blockIdx.x] = s[0];
}

__global__ __launch_bounds__(256) void scan_top(int* __restrict__ ws) {
    __shared__ int s[256];
    int t = threadIdx.x;
    int v = (t < NBLK) ? ws[BSUM_OFF + t] : 0;
    s[t] = v;
    __syncthreads();
    for (int d = 1; d < 256; d <<= 1) {
        int u = (t >= d) ? s[t - d] : 0;
        __syncthreads();
        s[t] += u;
        __syncthreads();
    }
    if (t < NBLK) ws[BSUM_OFF + t] = s[t] - v;           // exclusive
}

__global__ __launch_bounds__(256) void scan_off(int* __restrict__ ws) {
    __shared__ int s[256];
    int t = threadIdx.x;
    int idx = blockIdx.x * 256 + t;
    int c = (idx < NN) ? ws[CUR_OFF + idx] : 0;
    s[t] = c;
    __syncthreads();
    for (int d = 1; d < 256; d <<= 1) {
        int u = (t >= d) ? s[t - d] : 0;
        __syncthreads();
        s[t] += u;
        __syncthreads();
    }
    int off = ws[BSUM_OFF + blockIdx.x] + s[t] - c;      // exclusive prefix
    if (idx <= NN) {
        ws[OFF_OFF + idx] = off;
        if (idx < NN) ws[CUR_OFF + idx] = off;
    }
}

// fill: ONE packed 4 B write per edge -> one random cache line, not two
__global__ void fill_kernel(const int* __restrict__ eraw,
                            const uint16_t* __restrict__ ewraw,
                            int* __restrict__ ws) {
    int e = blockIdx.x * 256 + threadIdx.x;              // grid 3125 exact
    const int f32 = ws[0], i64 = ws[1];
    int src, dst;
    if (i64) {
        const long long* e64 = (const long long*)eraw;
        src = (int)e64[e];
        dst = (int)e64[NE + e];
    } else {
        src = eraw[e];
        dst = eraw[NE + e];
    }
    if ((unsigned)src >= NN || (unsigned)dst >= NN) return;
    uint w = f32 ? (uint)f2b(((const float*)ewraw)[e]) : (uint)ewraw[e];
    int slot = atomicAdd(ws + CUR_OFF + dst, 1);
    ((uint*)(ws + BKT_OFF))[slot] = (w << 16) | (uint)src;
}

// ---------------- fused gather-max + MFMA MLP ----------------
// 16 nodes/block, 4 waves. Gather: each wave computes 4 nodes (lane = dim pair)
// into LDS t-tile (bf16, padded stride). Then 2x(16x16) col-tiles/wave MFMA.
// A[m=lane&15][k=quad*8+j]; C/D: col=lane&15, row=quad*4+reg.
__global__ __launch_bounds__(256) void gmlp_kernel(
    const uint16_t* __restrict__ xraw,
    const uint16_t* __restrict__ b1raw,
    const uint16_t* __restrict__ b2raw,
    const uint16_t* __restrict__ epsraw,
    const int* __restrict__ ws,
    uint16_t* __restrict__ outraw)
{
    __shared__ uint   tl[16 * (HSTRIDE / 2)];   // t tile, 68 uints/row
    __shared__ ushort hl[16 * HSTRIDE];         // hidden tile

    const int tid  = threadIdx.x;
    const int wave = tid >> 6;
    const int lane = tid & 63;
    const int m    = lane & 15;
    const int quad = lane >> 4;
    const int node0 = blockIdx.x * 16;
    const int f32  = ws[0];

    const ushort* w1b = (const ushort*)(ws + WBF_OFF);
    const ushort* w2b = w1b + 16384;
    const uint*   xbf = (const uint*)(ws + XBF_OFF);
    const uint*   bkt = (const uint*)(ws + BKT_OFF);

    // hoist W1 B-frags + bias so global-load latency hides under the gather
    short8 bf1[2][4];
    float  bias1[2];
    #pragma unroll
    for (int t = 0; t < 2; ++t) {
        int ct = wave * 2 + t;
        const ushort* brow = w1b + (size_t)(ct * 16 + m) * 128 + quad * 8;
        #pragma unroll
        for (int kb = 0; kb < 4; ++kb) bf1[t][kb] = *(const short8*)(brow + kb * 32);
        bias1[t] = f32 ? ((const float*)b1raw)[ct * 16 + m] : b2f(b1raw[ct * 16 + m]);
    }
    const float eps1 = 1.0f + (f32 ? ((const float*)epsraw)[0] : b2f(epsraw[0]));

    // gather phase: 4 nodes per wave, lane covers dims (2*lane, 2*lane+1)
    for (int j = 0; j < 4; ++j) {
        int nl = wave * 4 + j;
        int n  = node0 + nl;
        int b = ws[OFF_OFF + n];
        int e = ws[OFF_OFF + n + 1];
        float a0 = NEG_INIT, a1 = NEG_INIT, p0 = NEG_INIT, p1 = NEG_INIT;
        float c0 = NEG_INIT, c1 = NEG_INIT, d0 = NEG_INIT, d1 = NEG_INIT;
        int i = b;
        for (; i + 4 <= e; i += 4) {
            uint e0 = bkt[i], e1 = bkt[i+1], e2 = bkt[i+2], e3 = bkt[i+3];
            uint v0 = xbf[(e0 & 0xffff) * 64 + lane];
            uint v1 = xbf[(e1 & 0xffff) * 64 + lane];
            uint v2 = xbf[(e2 & 0xffff) * 64 + lane];
            uint v3 = xbf[(e3 & 0xffff) * 64 + lane];
            float w0 = b2f((uint16_t)(e0 >> 16)), w1v = b2f((uint16_t)(e1 >> 16));
            float w2v = b2f((uint16_t)(e2 >> 16)), w3 = b2f((uint16_t)(e3 >> 16));
            a0 = fmaxf(a0, b2f((uint16_t)v0) * w0);  a1 = fmaxf(a1, b2f((uint16_t)(v0 >> 16)) * w0);
            p0 = fmaxf(p0, b2f((uint16_t)v1) * w1v); p1 = fmaxf(p1, b2f((uint16_t)(v1 >> 16)) * w1v);
            c0 = fmaxf(c0, b2f((uint16_t)v2) * w2v); c1 = fmaxf(c1, b2f((uint16_t)(v2 >> 16)) * w2v);
            d0 = fmaxf(d0, b2f((uint16_t)v3) * w3);  d1 = fmaxf(d1, b2f((uint16_t)(v3 >> 16)) * w3);
        }
        for (; i < e; ++i) {
            uint e0 = bkt[i];
            uint v = xbf[(e0 & 0xffff) * 64 + lane];
            float w = b2f((uint16_t)(e0 >> 16));
            a0 = fmaxf(a0, b2f((uint16_t)v) * w);
            a1 = fmaxf(a1, b2f((uint16_t)(v >> 16)) * w);
        }
        float mx = fmaxf(fmaxf(a0, p0), fmaxf(c0, d0));
        float my = fmaxf(fmaxf(a1, p1), fmaxf(c1, d1));
        if (b == e) { mx = 0.f; my = 0.f; }              // isolated node -> 0
        float xs0, xs1;
        if (f32) {
            float2 v = ((const float2*)xraw)[(size_t)n * 64 + lane];
            xs0 = v.x; xs1 = v.y;
        } else {
            uint v = ((const uint*)xraw)[(size_t)n * 64 + lane];
            xs0 = b2f((uint16_t)v); xs1 = b2f((uint16_t)(v >> 16));
        }
        float t0 = eps1 * xs0 + mx;
        float t1 = eps1 * xs1 + my;
        tl[nl * (HSTRIDE / 2) + lane] = (uint)f2b(t0) | ((uint)f2b(t1) << 16);
    }
    __syncthreads();

    // A frags from LDS t tile
    short8 a[4];
    {
        const ushort* arow = (const ushort*)tl + m * HSTRIDE + quad * 8;
        #pragma unroll
        for (int kb = 0; kb < 4; ++kb) a[kb] = *(const short8*)(arow + kb * 32);
    }

    // GEMM1 + bias + LeakyReLU -> hl
    #pragma unroll
    for (int t = 0; t < 2; ++t) {
        int ct = wave * 2 + t;
        float4v c = {0.f, 0.f, 0.f, 0.f};
        #pragma unroll
        for (int kb = 0; kb < 4; ++kb)
            c = __builtin_amdgcn_mfma_f32_16x16x32_bf16(a[kb], bf1[t][kb], c, 0, 0, 0);
        #pragma unroll
        for (int r = 0; r < 4; ++r) {
            float v = c[r] + bias1[t];
            v = (v >= 0.f) ? v : 0.01f * v;
            hl[(quad * 4 + r) * HSTRIDE + ct * 16 + m] = f2b(v);
        }
    }
    __syncthreads();

    // A frags for GEMM2 from hl
    short8 ah[4];
    {
        const ushort* hrow = hl + m * HSTRIDE + quad * 8;
        #pragma unroll
        for (int kb = 0; kb < 4; ++kb) ah[kb] = *(const short8*)(hrow + kb * 32);
    }

    // GEMM2 + bias -> out
    #pragma unroll
    for (int t = 0; t < 2; ++t) {
        int ct = wave * 2 + t;
        float4v c = {0.f, 0.f, 0.f, 0.f};
        const ushort* brow = w2b + (size_t)(ct * 16 + m) * 128 + quad * 8;
        #pragma unroll
        for (int kb = 0; kb < 4; ++kb)
            c = __builtin_amdgcn_mfma_f32_16x16x32_bf16(ah[kb], *(const short8*)(brow + kb * 32), c, 0, 0, 0);
        float bias = f32 ? ((const float*)b2raw)[ct * 16 + m] : b2f(b2raw[ct * 16 + m]);
        #pragma unroll
        for (int r = 0; r < 4; ++r) {
            float v = c[r] + bias;
            size_t o = (size_t)(node0 + quad * 4 + r) * 128 + ct * 16 + m;
            if (f32) ((float*)outraw)[o] = v;
            else     outraw[o] = f2b(v);
        }
    }
}

// ================= host =================
extern "C" void kernel_launch(void* const* d_in, const int* in_sizes, int n_in,
                              void* d_out, int out_size, void* d_ws, size_t ws_size,
                              hipStream_t stream) {
    const uint16_t* x    = (const uint16_t*)d_in[0];
    const int*      eidx = (const int*)     d_in[1];
    const uint16_t* ew   = (const uint16_t*)d_in[2];
    const uint16_t* w1   = (const uint16_t*)d_in[3];
    const uint16_t* b1   = (const uint16_t*)d_in[4];
    const uint16_t* w2   = (const uint16_t*)d_in[5];
    const uint16_t* b2   = (const uint16_t*)d_in[6];
    const uint16_t* eps  = (const uint16_t*)d_in[7];
    uint16_t*       out  = (uint16_t*)d_out;
    int* ws = (int*)d_ws;

    probe_kernel<<<1, 64, 0, stream>>>(x, eidx, ws);
    prep_kernel<<<6250 + 32 + NBLK, 256, 0, stream>>>(x, w1, w2, ws);
    hist_kernel<<<NE / 256, 256, 0, stream>>>(eidx, ws);
    scan_bsum<<<NBLK, 256, 0, stream>>>(ws);
    scan_top<<<1, 256, 0, stream>>>(ws);
    scan_off<<<NBLK, 256, 0, stream>>>(ws);
    fill_kernel<<<NE / 256, 256, 0, stream>>>(eidx, ew, ws);
    gmlp_kernel<<<NN / 16, 256, 0, stream>>>(x, b1, b2, eps, ws, out);
}

// Round 7
// 216.863 us; speedup vs baseline: 1.2104x; 1.2104x over previous
//
#include <hip/hip_runtime.h>
#include <stdint.h>

#define NN 50000
#define NE 800000
#define D  128
#define NEG_INIT -1e9f
#define CAP 64                            // bucket capacity per node (Poisson(16) max ~45)
#define OVF_CAP 131072

// ---------------- ws layout (int offsets) ----------------
#define FLAGS_OFF   0                     // [0]=f32 flag, [1]=i64 flag
#define CNT_OFF     64                    // NN counters
#define OVF_CNT_OFF 50064                 // overflow counter
#define OVF_OFF     50068                 // OVF_CAP pairs (dst, entry)
#define BKT_OFF     312320                // NN*CAP packed entries: (w_bf16<<16)|src
#define XBF_OFF     3512320               // NN*D bf16 x = 3.2M ints
#define WBF_OFF     6712320               // w1+w2 bf16 = 16384 ints
// total: 6,728,704 ints = 26.9 MB (< 32.4 MB proven available in round 3)

#define NBLK 196                          // ceil(NN/256)
#define HSTRIDE 136                       // LDS row stride in ushorts (272 B, 2-way banks = free)

typedef __attribute__((ext_vector_type(8))) short short8;
typedef __attribute__((ext_vector_type(4))) float float4v;

// ---------------- bf16 helpers ----------------
__device__ __forceinline__ float b2f(uint16_t u) {
    union { uint32_t u; float f; } v; v.u = ((uint32_t)u) << 16; return v.f;
}
__device__ __forceinline__ uint16_t f2b(float f) {
    union { float f; uint32_t u; } v; v.f = f;
    uint32_t r = v.u + 0x7fffu + ((v.u >> 16) & 1u);   // RNE
    return (uint16_t)(r >> 16);
}

// ---------------- kernel 0: runtime dtype probe (load-bearing; rounds 2-4,6) ----------------
__global__ void probe_kernel(const uint16_t* __restrict__ xraw,
                             const int* __restrict__ eraw,
                             int* __restrict__ flags) {
    int t = threadIdx.x;   // 64 threads
    float v0 = b2f(xraw[2 * t]);
    float v1 = b2f(xraw[2 * t + 1]);
    int bad = (!(v0 > -1e4f && v0 < 1e4f)) || (!(v1 > -1e4f && v1 < 1e4f));
    unsigned long long bm = __ballot(bad);
    int nz = (t < 32) ? (eraw[2 * t + 1] != 0) : 0;
    unsigned long long im = __ballot(nz);
    if (t == 0) { flags[0] = bm ? 1 : 0; flags[1] = im ? 0 : 1; }
}

// ---------------- fused prep: x->bf16 | w1,w2->bf16 | zero counters ----------------
// grid = 6250 (x) + 32 (w) + NBLK (zero) = 6478 blocks
__global__ __launch_bounds__(256) void prep_kernel(
    const uint16_t* __restrict__ xraw,
    const uint16_t* __restrict__ w1raw,
    const uint16_t* __restrict__ w2raw,
    int* __restrict__ ws)
{
    int bid = blockIdx.x;
    const int f32 = ws[0];
    if (bid < 6250) {
        int i4 = (bid * 256 + threadIdx.x) * 4;          // covers NN*D = 6.4M exactly
        ushort* dst = (ushort*)(ws + XBF_OFF);
        if (f32) {
            float4 v = *(const float4*)((const float*)xraw + i4);
            ushort4 o; o.x = f2b(v.x); o.y = f2b(v.y); o.z = f2b(v.z); o.w = f2b(v.w);
            *(ushort4*)(dst + i4) = o;
        } else {
            *(ushort4*)(dst + i4) = *(const ushort4*)(xraw + i4);
        }
    } else if (bid < 6282) {
        int i4 = ((bid - 6250) * 256 + threadIdx.x) * 4; // 0..32764
        const uint16_t* src = (i4 < 16384) ? w1raw : w2raw;
        int off = i4 & 16383;
        ushort* dst = (ushort*)(ws + WBF_OFF);
        if (f32) {
            float4 v = *(const float4*)((const float*)src + off);
            ushort4 o; o.x = f2b(v.x); o.y = f2b(v.y); o.z = f2b(v.z); o.w = f2b(v.w);
            *(ushort4*)(dst + i4) = o;
        } else {
            *(ushort4*)(dst + i4) = *(const ushort4*)(src + off);
        }
    } else {
        int i = (bid - 6282) * 256 + threadIdx.x;
        if (i < NN) ws[CNT_OFF + i] = 0;
        if (i == 0)  ws[OVF_CNT_OFF] = 0;
    }
}

// ---------------- direct bucket fill: ONE kernel replaces hist+scan x3+fill ----------------
__global__ void fill_kernel(const int* __restrict__ eraw,
                            const uint16_t* __restrict__ ewraw,
                            int* __restrict__ ws) {
    int e = blockIdx.x * 256 + threadIdx.x;              // grid 3125 exact
    const int f32 = ws[0], i64 = ws[1];
    int src, dst;
    if (i64) {
        const long long* e64 = (const long long*)eraw;
        src = (int)e64[e];
        dst = (int)e64[NE + e];
    } else {
        src = eraw[e];
        dst = eraw[NE + e];
    }
    if ((unsigned)src >= NN || (unsigned)dst >= NN) return;
    uint w = f32 ? (uint)f2b(((const float*)ewraw)[e]) : (uint)ewraw[e];
    uint entry = (w << 16) | (uint)src;
    int slot = atomicAdd(ws + CNT_OFF + dst, 1);
    if (slot < CAP) {
        ((uint*)(ws + BKT_OFF))[(size_t)dst * CAP + slot] = entry;
    } else {
        int o = atomicAdd(ws + OVF_CNT_OFF, 1);
        if (o < OVF_CAP) {
            ws[OVF_OFF + 2 * o]     = dst;
            ws[OVF_OFF + 2 * o + 1] = (int)entry;
        }
    }
}

// ---------------- fused gather-max + MFMA MLP ----------------
// 16 nodes/block, 4 waves; wave gathers 4 nodes (lane = dim pair), unroll-8
// with clamped-index predication (8 outstanding row-gathers). Then MFMA.
// A[m=lane&15][k=quad*8+j]; C/D: col=lane&15, row=quad*4+reg.
__global__ __launch_bounds__(256) void gmlp_kernel(
    const uint16_t* __restrict__ xraw,
    const uint16_t* __restrict__ b1raw,
    const uint16_t* __restrict__ b2raw,
    const uint16_t* __restrict__ epsraw,
    const int* __restrict__ ws,
    uint16_t* __restrict__ outraw)
{
    __shared__ uint   tl[16 * (HSTRIDE / 2)];   // t tile, 68 uints/row
    __shared__ ushort hl[16 * HSTRIDE];         // hidden tile

    const int tid  = threadIdx.x;
    const int wave = tid >> 6;
    const int lane = tid & 63;
    const int m    = lane & 15;
    const int quad = lane >> 4;
    const int node0 = blockIdx.x * 16;
    const int f32  = ws[0];

    const ushort* w1b = (const ushort*)(ws + WBF_OFF);
    const ushort* w2b = w1b + 16384;
    const uint*   xbf = (const uint*)(ws + XBF_OFF);
    const uint*   bkt = (const uint*)(ws + BKT_OFF);

    // hoist W1 B-frags + bias so global-load latency hides under the gather
    short8 bf1[2][4];
    float  bias1[2];
    #pragma unroll
    for (int t = 0; t < 2; ++t) {
        int ct = wave * 2 + t;
        const ushort* brow = w1b + (size_t)(ct * 16 + m) * 128 + quad * 8;
        #pragma unroll
        for (int kb = 0; kb < 4; ++kb) bf1[t][kb] = *(const short8*)(brow + kb * 32);
        bias1[t] = f32 ? ((const float*)b1raw)[ct * 16 + m] : b2f(b1raw[ct * 16 + m]);
    }
    const float eps1 = 1.0f + (f32 ? ((const float*)epsraw)[0] : b2f(epsraw[0]));

    // gather phase: 4 nodes per wave, lane covers dims (2*lane, 2*lane+1)
    for (int j = 0; j < 4; ++j) {
        int nl = wave * 4 + j;
        int n  = node0 + nl;
        int cnt_raw = ws[CNT_OFF + n];
        int cnt = (cnt_raw < CAP) ? cnt_raw : CAP;

        float m0[8], m1[8];
        #pragma unroll
        for (int u = 0; u < 8; ++u) { m0[u] = NEG_INIT; m1[u] = NEG_INIT; }

        const uint* brow = bkt + (size_t)n * CAP;
        for (int i = 0; i < cnt; i += 8) {
            #pragma unroll
            for (int u = 0; u < 8; ++u) {
                int idx  = i + u;
                int idxc = (idx < cnt - 1) ? idx : cnt - 1;   // clamp (cnt>0 here)
                uint e0  = brow[idxc];
                uint v   = xbf[(e0 & 0xffff) * 64 + lane];
                float w  = b2f((uint16_t)(e0 >> 16));
                float p0 = b2f((uint16_t)v) * w;
                float p1 = b2f((uint16_t)(v >> 16)) * w;
                bool ok  = idx < cnt;
                m0[u] = fmaxf(m0[u], ok ? p0 : NEG_INIT);
                m1[u] = fmaxf(m1[u], ok ? p1 : NEG_INIT);
            }
        }
        // overflow edges (exactness insurance; statistically never taken)
        if (cnt_raw > CAP) {
            int novf = ws[OVF_CNT_OFF];
            if (novf > OVF_CAP) novf = OVF_CAP;
            for (int o = 0; o < novf; ++o) {
                if (ws[OVF_OFF + 2 * o] == n) {
                    uint e0 = (uint)ws[OVF_OFF + 2 * o + 1];
                    uint v  = xbf[(e0 & 0xffff) * 64 + lane];
                    float w = b2f((uint16_t)(e0 >> 16));
                    m0[0] = fmaxf(m0[0], b2f((uint16_t)v) * w);
                    m1[0] = fmaxf(m1[0], b2f((uint16_t)(v >> 16)) * w);
                }
            }
        }
        #pragma unroll
        for (int u = 4; u > 0; u >>= 1)
            #pragma unroll
            for (int v = 0; v < u; ++v) {
                m0[v] = fmaxf(m0[v], m0[v + u]);
                m1[v] = fmaxf(m1[v], m1[v + u]);
            }
        float mx = m0[0], my = m1[0];
        if (cnt_raw == 0) { mx = 0.f; my = 0.f; }        // isolated node -> 0

        float xs0, xs1;
        if (f32) {
            float2 v = ((const float2*)xraw)[(size_t)n * 64 + lane];
            xs0 = v.x; xs1 = v.y;
        } else {
            uint v = ((const uint*)xraw)[(size_t)n * 64 + lane];
            xs0 = b2f((uint16_t)v); xs1 = b2f((uint16_t)(v >> 16));
        }
        float t0 = eps1 * xs0 + mx;
        float t1 = eps1 * xs1 + my;
        tl[nl * (HSTRIDE / 2) + lane] = (uint)f2b(t0) | ((uint)f2b(t1) << 16);
    }
    __syncthreads();

    // A frags from LDS t tile
    short8 a[4];
    {
        const ushort* arow = (const ushort*)tl + m * HSTRIDE + quad * 8;
        #pragma unroll
        for (int kb = 0; kb < 4; ++kb) a[kb] = *(const short8*)(arow + kb * 32);
    }

    // GEMM1 + bias + LeakyReLU -> hl
    #pragma unroll
    for (int t = 0; t < 2; ++t) {
        int ct = wave * 2 + t;
        float4v c = {0.f, 0.f, 0.f, 0.f};
        #pragma unroll
        for (int kb = 0; kb < 4; ++kb)
            c = __builtin_amdgcn_mfma_f32_16x16x32_bf16(a[kb], bf1[t][kb], c, 0, 0, 0);
        #pragma unroll
        for (int r = 0; r < 4; ++r) {
            float v = c[r] + bias1[t];
            v = (v >= 0.f) ? v : 0.01f * v;
            hl[(quad * 4 + r) * HSTRIDE + ct * 16 + m] = f2b(v);
        }
    }
    __syncthreads();

    // A frags for GEMM2 from hl
    short8 ah[4];
    {
        const ushort* hrow = hl + m * HSTRIDE + quad * 8;
        #pragma unroll
        for (int kb = 0; kb < 4; ++kb) ah[kb] = *(const short8*)(hrow + kb * 32);
    }

    // GEMM2 + bias -> out
    #pragma unroll
    for (int t = 0; t < 2; ++t) {
        int ct = wave * 2 + t;
        float4v c = {0.f, 0.f, 0.f, 0.f};
        const ushort* brow = w2b + (size_t)(ct * 16 + m) * 128 + quad * 8;
        #pragma unroll
        for (int kb = 0; kb < 4; ++kb)
            c = __builtin_amdgcn_mfma_f32_16x16x32_bf16(ah[kb], *(const short8*)(brow + kb * 32), c, 0, 0, 0);
        float bias = f32 ? ((const float*)b2raw)[ct * 16 + m] : b2f(b2raw[ct * 16 + m]);
        #pragma unroll
        for (int r = 0; r < 4; ++r) {
            float v = c[r] + bias;
            size_t o = (size_t)(node0 + quad * 4 + r) * 128 + ct * 16 + m;
            if (f32) ((float*)outraw)[o] = v;
            else     outraw[o] = f2b(v);
        }
    }
}

// ================= host =================
extern "C" void kernel_launch(void* const* d_in, const int* in_sizes, int n_in,
                              void* d_out, int out_size, void* d_ws, size_t ws_size,
                              hipStream_t stream) {
    const uint16_t* x    = (const uint16_t*)d_in[0];
    const int*      eidx = (const int*)     d_in[1];
    const uint16_t* ew   = (const uint16_t*)d_in[2];
    const uint16_t* w1   = (const uint16_t*)d_in[3];
    const uint16_t* b1   = (const uint16_t*)d_in[4];
    const uint16_t* w2   = (const uint16_t*)d_in[5];
    const uint16_t* b2   = (const uint16_t*)d_in[6];
    const uint16_t* eps  = (const uint16_t*)d_in[7];
    uint16_t*       out  = (uint16_t*)d_out;
    int* ws = (int*)d_ws;

    probe_kernel<<<1, 64, 0, stream>>>(x, eidx, ws);
    prep_kernel<<<6250 + 32 + NBLK, 256, 0, stream>>>(x, w1, w2, ws);
    fill_kernel<<<NE / 256, 256, 0, stream>>>(eidx, ew, ws);
    gmlp_kernel<<<NN / 16, 256, 0, stream>>>(x, b1, b2, eps, ws, out);
}

// Round 8
// 209.825 us; speedup vs baseline: 1.2510x; 1.0335x over previous
//
#include <hip/hip_runtime.h>
#include <stdint.h>

#define NN 50000
#define NE 800000
#define D  128
#define NEG_INIT -1e9f
#define CAP 64                            // bucket capacity per node (Poisson(16); P(deg>64)~1e-19)
#define OVF_CAP 131072

// ---------------- ws layout (int offsets) ----------------
#define CNT_OFF     64                    // NN counters
#define OVF_CNT_OFF 50064                 // overflow counter
#define OVF_OFF     50068                 // OVF_CAP pairs (dst, entry)
#define BKT_OFF     312320                // NN*CAP packed entries: (w_bf16<<16)|src
#define XBF_OFF     3512320               // NN*D bf16 x = 3.2M ints
#define WBF_OFF     6712320               // w1+w2 bf16 = 16384 ints
// total: 6,728,704 ints = 26.9 MB (< 32.4 MB proven available)

#define NBLK 196                          // ceil(NN/256)
#define HSTRIDE 136                       // LDS row stride in ushorts (272 B, 2-way banks = free)

typedef __attribute__((ext_vector_type(8))) short short8;
typedef __attribute__((ext_vector_type(4))) float float4v;

// ---------------- bf16 helpers ----------------
__device__ __forceinline__ float b2f(uint16_t u) {
    union { uint32_t u; float f; } v; v.u = ((uint32_t)u) << 16; return v.f;
}
__device__ __forceinline__ uint16_t f2b(float f) {
    union { float f; uint32_t u; } v; v.f = f;
    uint32_t r = v.u + 0x7fffu + ((v.u >> 16) & 1u);   // RNE
    return (uint16_t)(r >> 16);
}

// ---------------- per-block inline dtype probe (replaces probe kernel) ----------------
// sflags[0]=1 if float tensors are fp32; sflags[1]=1 if edge_index is int64
__device__ __forceinline__ void block_probe(const uint16_t* __restrict__ xraw,
                                            const int* __restrict__ eraw,
                                            int* sflags) {
    int t = threadIdx.x;
    if (t < 64) {                                   // wave 0 only
        float v0 = b2f(xraw[2 * t]);
        float v1 = b2f(xraw[2 * t + 1]);
        int bad = (!(v0 > -1e4f && v0 < 1e4f)) || (!(v1 > -1e4f && v1 < 1e4f));
        unsigned long long bm = __ballot(bad);
        int nz = (t < 32) ? (eraw[2 * t + 1] != 0) : 0;
        unsigned long long im = __ballot(nz);
        if (t == 0) { sflags[0] = bm ? 1 : 0; sflags[1] = im ? 0 : 1; }
    }
    __syncthreads();
}

// ---------------- fused prep: x->bf16 | w1,w2->bf16 | zero counters ----------------
// grid = 6250 (x) + 32 (w) + NBLK (zero) = 6478 blocks
__global__ __launch_bounds__(256) void prep_kernel(
    const uint16_t* __restrict__ xraw,
    const int*      __restrict__ eraw,
    const uint16_t* __restrict__ w1raw,
    const uint16_t* __restrict__ w2raw,
    int* __restrict__ ws)
{
    __shared__ int sflags[2];
    block_probe(xraw, eraw, sflags);
    const int f32 = sflags[0];

    int bid = blockIdx.x;
    if (bid < 6250) {
        int i4 = (bid * 256 + threadIdx.x) * 4;          // covers NN*D = 6.4M exactly
        ushort* dst = (ushort*)(ws + XBF_OFF);
        if (f32) {
            float4 v = *(const float4*)((const float*)xraw + i4);
            ushort4 o; o.x = f2b(v.x); o.y = f2b(v.y); o.z = f2b(v.z); o.w = f2b(v.w);
            *(ushort4*)(dst + i4) = o;
        } else {
            *(ushort4*)(dst + i4) = *(const ushort4*)(xraw + i4);
        }
    } else if (bid < 6282) {
        int i4 = ((bid - 6250) * 256 + threadIdx.x) * 4; // 0..32764
        const uint16_t* src = (i4 < 16384) ? w1raw : w2raw;
        int off = i4 & 16383;
        ushort* dst = (ushort*)(ws + WBF_OFF);
        if (f32) {
            float4 v = *(const float4*)((const float*)src + off);
            ushort4 o; o.x = f2b(v.x); o.y = f2b(v.y); o.z = f2b(v.z); o.w = f2b(v.w);
            *(ushort4*)(dst + i4) = o;
        } else {
            *(ushort4*)(dst + i4) = *(const ushort4*)(src + off);
        }
    } else {
        int i = (bid - 6282) * 256 + threadIdx.x;
        if (i < NN) ws[CNT_OFF + i] = 0;
        if (i == 0)  ws[OVF_CNT_OFF] = 0;
    }
}

// ---------------- direct bucket fill ----------------
__global__ __launch_bounds__(256) void fill_kernel(
    const uint16_t* __restrict__ xraw,
    const int*      __restrict__ eraw,
    const uint16_t* __restrict__ ewraw,
    int* __restrict__ ws)
{
    __shared__ int sflags[2];
    block_probe(xraw, eraw, sflags);
    const int f32 = sflags[0], i64 = sflags[1];

    int e = blockIdx.x * 256 + threadIdx.x;              // grid 3125 exact
    int src, dst;
    if (i64) {
        const long long* e64 = (const long long*)eraw;
        src = (int)e64[e];
        dst = (int)e64[NE + e];
    } else {
        src = eraw[e];
        dst = eraw[NE + e];
    }
    if ((unsigned)src >= NN || (unsigned)dst >= NN) return;
    uint w = f32 ? (uint)f2b(((const float*)ewraw)[e]) : (uint)ewraw[e];
    uint entry = (w << 16) | (uint)src;
    int slot = atomicAdd(ws + CNT_OFF + dst, 1);
    if (slot < CAP) {
        ((uint*)(ws + BKT_OFF))[(size_t)dst * CAP + slot] = entry;
    } else {
        int o = atomicAdd(ws + OVF_CNT_OFF, 1);
        if (o < OVF_CAP) {
            ws[OVF_OFF + 2 * o]     = dst;
            ws[OVF_OFF + 2 * o + 1] = (int)entry;
        }
    }
}

// ---------------- fused gather-max + MFMA MLP ----------------
// 16 nodes/block, 4 waves; wave gathers 4 nodes (lane = dim pair), unroll-16
// with uint4 bucket-entry loads (16 outstanding row-gathers). Then MFMA.
// A[m=lane&15][k=quad*8+j]; C/D: col=lane&15, row=quad*4+reg.
__global__ __launch_bounds__(256) void gmlp_kernel(
    const uint16_t* __restrict__ xraw,
    const int*      __restrict__ eraw,
    const uint16_t* __restrict__ b1raw,
    const uint16_t* __restrict__ b2raw,
    const uint16_t* __restrict__ epsraw,
    const int* __restrict__ ws,
    uint16_t* __restrict__ outraw)
{
    __shared__ int    sflags[2];
    __shared__ uint   tl[16 * (HSTRIDE / 2)];   // t tile, 68 uints/row
    __shared__ ushort hl[16 * HSTRIDE];         // hidden tile

    block_probe(xraw, eraw, sflags);
    const int f32 = sflags[0];

    const int tid  = threadIdx.x;
    const int wave = tid >> 6;
    const int lane = tid & 63;
    const int m    = lane & 15;
    const int quad = lane >> 4;
    const int node0 = blockIdx.x * 16;

    const ushort* w1b = (const ushort*)(ws + WBF_OFF);
    const ushort* w2b = w1b + 16384;
    const uint*   xbf = (const uint*)(ws + XBF_OFF);
    const uint*   bkt = (const uint*)(ws + BKT_OFF);

    const float eps1 = 1.0f + (f32 ? ((const float*)epsraw)[0] : b2f(epsraw[0]));

    // gather phase: 4 nodes per wave, lane covers dims (2*lane, 2*lane+1)
    for (int j = 0; j < 4; ++j) {
        int nl = wave * 4 + j;
        int n  = node0 + nl;
        int cnt_raw = ws[CNT_OFF + n];
        int cnt = (cnt_raw < CAP) ? cnt_raw : CAP;

        float m0[16], m1[16];
        #pragma unroll
        for (int u = 0; u < 16; ++u) { m0[u] = NEG_INIT; m1[u] = NEG_INIT; }

        const uint* brow = bkt + (size_t)n * CAP;
        for (int i = 0; i < cnt; i += 16) {
            uint4 q[4];
            #pragma unroll
            for (int qq = 0; qq < 4; ++qq) q[qq] = *(const uint4*)(brow + i + qq * 4);
            #pragma unroll
            for (int u = 0; u < 16; ++u) {
                uint e0 = ((const uint*)q)[u];
                bool ok = (i + u) < cnt;
                uint idx = ok ? (e0 & 0xffffu) : 0u;      // masked lanes gather row 0 (hot)
                uint v = xbf[idx * 64 + lane];
                float w  = b2f((uint16_t)(e0 >> 16));
                float p0 = b2f((uint16_t)v) * w;
                float p1 = b2f((uint16_t)(v >> 16)) * w;
                m0[u] = fmaxf(m0[u], ok ? p0 : NEG_INIT);
                m1[u] = fmaxf(m1[u], ok ? p1 : NEG_INIT);
            }
        }
        // overflow edges (exactness insurance; statistically never taken)
        if (cnt_raw > CAP) {
            int novf = ws[OVF_CNT_OFF];
            if (novf > OVF_CAP) novf = OVF_CAP;
            for (int o = 0; o < novf; ++o) {
                if (ws[OVF_OFF + 2 * o] == n) {
                    uint e0 = (uint)ws[OVF_OFF + 2 * o + 1];
                    uint v  = xbf[(e0 & 0xffff) * 64 + lane];
                    float w = b2f((uint16_t)(e0 >> 16));
                    m0[0] = fmaxf(m0[0], b2f((uint16_t)v) * w);
                    m1[0] = fmaxf(m1[0], b2f((uint16_t)(v >> 16)) * w);
                }
            }
        }
        #pragma unroll
        for (int u = 8; u > 0; u >>= 1)
            #pragma unroll
            for (int v2 = 0; v2 < u; ++v2) {
                m0[v2] = fmaxf(m0[v2], m0[v2 + u]);
                m1[v2] = fmaxf(m1[v2], m1[v2 + u]);
            }
        float mx = m0[0], my = m1[0];
        if (cnt_raw == 0) { mx = 0.f; my = 0.f; }        // isolated node -> 0

        // self term from bf16 table (cache-hot; saves the 25.6 MB fp32 stream)
        uint xv = xbf[(size_t)n * 64 + lane];
        float t0 = eps1 * b2f((uint16_t)xv) + mx;
        float t1 = eps1 * b2f((uint16_t)(xv >> 16)) + my;
        tl[nl * (HSTRIDE / 2) + lane] = (uint)f2b(t0) | ((uint)f2b(t1) << 16);
    }
    __syncthreads();

    // A frags from LDS t tile
    short8 a[4];
    {
        const ushort* arow = (const ushort*)tl + m * HSTRIDE + quad * 8;
        #pragma unroll
        for (int kb = 0; kb < 4; ++kb) a[kb] = *(const short8*)(arow + kb * 32);
    }

    // GEMM1 + bias + LeakyReLU -> hl
    #pragma unroll
    for (int t = 0; t < 2; ++t) {
        int ct = wave * 2 + t;
        float4v c = {0.f, 0.f, 0.f, 0.f};
        const ushort* brow = w1b + (size_t)(ct * 16 + m) * 128 + quad * 8;
        #pragma unroll
        for (int kb = 0; kb < 4; ++kb)
            c = __builtin_amdgcn_mfma_f32_16x16x32_bf16(a[kb], *(const short8*)(brow + kb * 32), c, 0, 0, 0);
        float bias = f32 ? ((const float*)b1raw)[ct * 16 + m] : b2f(b1raw[ct * 16 + m]);
        #pragma unroll
        for (int r = 0; r < 4; ++r) {
            float v = c[r] + bias;
            v = (v >= 0.f) ? v : 0.01f * v;
            hl[(quad * 4 + r) * HSTRIDE + ct * 16 + m] = f2b(v);
        }
    }
    __syncthreads();

    // A frags for GEMM2 from hl
    short8 ah[4];
    {
        const ushort* hrow = hl + m * HSTRIDE + quad * 8;
        #pragma unroll
        for (int kb = 0; kb < 4; ++kb) ah[kb] = *(const short8*)(hrow + kb * 32);
    }

    // GEMM2 + bias -> out
    #pragma unroll
    for (int t = 0; t < 2; ++t) {
        int ct = wave * 2 + t;
        float4v c = {0.f, 0.f, 0.f, 0.f};
        const ushort* brow = w2b + (size_t)(ct * 16 + m) * 128 + quad * 8;
        #pragma unroll
        for (int kb = 0; kb < 4; ++kb)
            c = __builtin_amdgcn_mfma_f32_16x16x32_bf16(ah[kb], *(const short8*)(brow + kb * 32), c, 0, 0, 0);
        float bias = f32 ? ((const float*)b2raw)[ct * 16 + m] : b2f(b2raw[ct * 16 + m]);
        #pragma unroll
        for (int r = 0; r < 4; ++r) {
            float v = c[r] + bias;
            size_t o = (size_t)(node0 + quad * 4 + r) * 128 + ct * 16 + m;
            if (f32) ((float*)outraw)[o] = v;
            else     outraw[o] = f2b(v);
        }
    }
}

// ================= host =================
extern "C" void kernel_launch(void* const* d_in, const int* in_sizes, int n_in,
                              void* d_out, int out_size, void* d_ws, size_t ws_size,
                              hipStream_t stream) {
    const uint16_t* x    = (const uint16_t*)d_in[0];
    const int*      eidx = (const int*)     d_in[1];
    const uint16_t* ew   = (const uint16_t*)d_in[2];
    const uint16_t* w1   = (const uint16_t*)d_in[3];
    const uint16_t* b1   = (const uint16_t*)d_in[4];
    const uint16_t* w2   = (const uint16_t*)d_in[5];
    const uint16_t* b2   = (const uint16_t*)d_in[6];
    const uint16_t* eps  = (const uint16_t*)d_in[7];
    uint16_t*       out  = (uint16_t*)d_out;
    int* ws = (int*)d_ws;

    prep_kernel<<<6250 + 32 + NBLK, 256, 0, stream>>>(x, eidx, w1, w2, ws);
    fill_kernel<<<NE / 256, 256, 0, stream>>>(x, eidx, ew, ws);
    gmlp_kernel<<<NN / 16, 256, 0, stream>>>(x, eidx, b1, b2, eps, ws, out);
}